// Round 4
// baseline (1868.907 us; speedup 1.0000x reference)
//
#include <hip/hip_runtime.h>

#define BLOCK 1024   // 16 waves of 64
#define CHUNK 16     // amps per LDS exchange chunk (128 KB buffer)

// ---------- state: 32 named float2 members, compile-time indexed ----------
struct St {
  float2 a0,a1,a2,a3,a4,a5,a6,a7,a8,a9,a10,a11,a12,a13,a14,a15,
         a16,a17,a18,a19,a20,a21,a22,a23,a24,a25,a26,a27,a28,a29,a30,a31;
  template<int I> __device__ __forceinline__ float2& g(){
    if constexpr (I==0) return a0;   else if constexpr (I==1) return a1;
    else if constexpr (I==2) return a2;   else if constexpr (I==3) return a3;
    else if constexpr (I==4) return a4;   else if constexpr (I==5) return a5;
    else if constexpr (I==6) return a6;   else if constexpr (I==7) return a7;
    else if constexpr (I==8) return a8;   else if constexpr (I==9) return a9;
    else if constexpr (I==10) return a10; else if constexpr (I==11) return a11;
    else if constexpr (I==12) return a12; else if constexpr (I==13) return a13;
    else if constexpr (I==14) return a14; else if constexpr (I==15) return a15;
    else if constexpr (I==16) return a16; else if constexpr (I==17) return a17;
    else if constexpr (I==18) return a18; else if constexpr (I==19) return a19;
    else if constexpr (I==20) return a20; else if constexpr (I==21) return a21;
    else if constexpr (I==22) return a22; else if constexpr (I==23) return a23;
    else if constexpr (I==24) return a24; else if constexpr (I==25) return a25;
    else if constexpr (I==26) return a26; else if constexpr (I==27) return a27;
    else if constexpr (I==28) return a28; else if constexpr (I==29) return a29;
    else if constexpr (I==30) return a30; else return a31;
  }
};

__device__ __forceinline__ float2 cmadd2(float2 u, float2 a, float2 v, float2 b){
  // u*a + v*b (complex)
  return make_float2(u.x*a.x - u.y*a.y + v.x*b.x - v.y*b.y,
                     u.x*a.y + u.y*a.x + v.x*b.y + v.y*b.x);
}

// ================= template-recursive gate bodies (no lambdas, no arrays) =================

// ---- rotation on a local bit BL (0..4) ----
template<int BL, int K>
__device__ __forceinline__ void rot_local_impl(St& st, float2 u00, float2 u01, float2 u10, float2 u11){
  if constexpr (K < 32){
    if constexpr (!(K & (1<<BL))){
      constexpr int K1 = K | (1<<BL);
      float2 x0 = st.g<K>(), x1 = st.g<K1>();
      st.g<K>()  = cmadd2(u00, x0, u01, x1);
      st.g<K1>() = cmadd2(u10, x0, u11, x1);
    }
    rot_local_impl<BL, K+1>(st, u00, u01, u10, u11);
  }
}
template<int BL>
__device__ __forceinline__ void rot_local(St& st, const float* u){
  float2 u00 = make_float2(u[0],u[1]), u01 = make_float2(u[2],u[3]);
  float2 u10 = make_float2(u[4],u[5]), u11 = make_float2(u[6],u[7]);
  rot_local_impl<BL, 0>(st, u00, u01, u10, u11);
}

// ---- rotation on a lane bit LB (0..5): wave shuffle ----
template<int LB, int K>
__device__ __forceinline__ void rot_lane_impl(St& st, float2 ua, float2 ub){
  if constexpr (K < 32){
    float2 A = st.g<K>();
    float2 p;
    p.x = __shfl_xor(A.x, 1<<LB, 64);
    p.y = __shfl_xor(A.y, 1<<LB, 64);
    st.g<K>() = cmadd2(ua, A, ub, p);
    rot_lane_impl<LB, K+1>(st, ua, ub);
  }
}
template<int LB>
__device__ __forceinline__ void rot_lane(St& st, const float* u, int lane){
  const int bit = (lane >> LB) & 1;
  float2 u00 = make_float2(u[0],u[1]), u01 = make_float2(u[2],u[3]);
  float2 u10 = make_float2(u[4],u[5]), u11 = make_float2(u[6],u[7]);
  float2 ua = bit ? u11 : u00;
  float2 ub = bit ? u10 : u01;
  rot_lane_impl<LB, 0>(st, ua, ub);
}

// ---- LDS staging helpers (compile-time chunk index) ----
template<int Base, int K>
__device__ __forceinline__ void stw_impl(St& st, float2* xbuf, int t){
  if constexpr (K < CHUNK){
    xbuf[K*BLOCK + t] = st.g<Base + K>();
    stw_impl<Base, K+1>(st, xbuf, t);
  }
}
template<int Base, int K>
__device__ __forceinline__ void ldr_rot_impl(St& st, const float2* xbuf, int partner, float2 ua, float2 ub){
  if constexpr (K < CHUNK){
    float2 p = xbuf[K*BLOCK + partner];
    float2 A = st.g<Base + K>();
    st.g<Base + K>() = cmadd2(ua, A, ub, p);
    ldr_rot_impl<Base, K+1>(st, xbuf, partner, ua, ub);
  }
}
template<int Base, int K>
__device__ __forceinline__ void ldr_swap_impl(St& st, const float2* xbuf, int partner){
  if constexpr (K < CHUNK){
    st.g<Base + K>() = xbuf[K*BLOCK + partner];
    ldr_swap_impl<Base, K+1>(st, xbuf, partner);
  }
}

// ---- rotation on a wave bit WB (0..3): LDS exchange ----
template<int WB>
__device__ __forceinline__ void rot_wave(St& st, const float* u, int t, float2* xbuf){
  const int partner = t ^ (64 << WB);
  const int bit = (t >> (6 + WB)) & 1;
  float2 u00 = make_float2(u[0],u[1]), u01 = make_float2(u[2],u[3]);
  float2 u10 = make_float2(u[4],u[5]), u11 = make_float2(u[6],u[7]);
  float2 ua = bit ? u11 : u00;
  float2 ub = bit ? u10 : u01;
  __syncthreads();                       // prior reads of xbuf done
  stw_impl<0, 0>(st, xbuf, t);
  __syncthreads();
  ldr_rot_impl<0, 0>(st, xbuf, partner, ua, ub);
  __syncthreads();
  stw_impl<16, 0>(st, xbuf, t);
  __syncthreads();
  ldr_rot_impl<16, 0>(st, xbuf, partner, ua, ub);
}

// ---- CNOT, both bits local ----
template<int BC, int BT, int K>
__device__ __forceinline__ void cnot_local_impl(St& st){
  if constexpr (K < 32){
    if constexpr ((K & (1<<BC)) && !(K & (1<<BT))){
      constexpr int K1 = K | (1<<BT);
      float2 tmp = st.g<K>(); st.g<K>() = st.g<K1>(); st.g<K1>() = tmp;
    }
    cnot_local_impl<BC, BT, K+1>(st);
  }
}
template<int BC, int BT>
__device__ __forceinline__ void cnot_local(St& st){ cnot_local_impl<BC, BT, 0>(st); }

// ---- CNOT, control = per-thread bool, target local bit BT ----
template<int BT, int K>
__device__ __forceinline__ void cnot_cl_impl(St& st, bool ctrl){
  if constexpr (K < 32){
    if constexpr (!(K & (1<<BT))){
      constexpr int K1 = K | (1<<BT);
      float2 x0 = st.g<K>(), x1 = st.g<K1>();
      st.g<K>()  = ctrl ? x1 : x0;
      st.g<K1>() = ctrl ? x0 : x1;
    }
    cnot_cl_impl<BT, K+1>(st, ctrl);
  }
}
template<int BT>
__device__ __forceinline__ void cnot_cl(St& st, bool ctrl){ cnot_cl_impl<BT, 0>(st, ctrl); }

// ---- CNOT, target = lane bit (shfl mask M), control = per-thread bool ----
template<int M, int K>
__device__ __forceinline__ void cnot_shfl_impl(St& st, bool ctrl){
  if constexpr (K < 32){
    float2 A = st.g<K>();
    float2 p;
    p.x = __shfl_xor(A.x, M, 64);
    p.y = __shfl_xor(A.y, M, 64);
    if (ctrl) st.g<K>() = p;
    cnot_shfl_impl<M, K+1>(st, ctrl);
  }
}
template<int M>
__device__ __forceinline__ void cnot_shfl(St& st, bool ctrl){ cnot_shfl_impl<M, 0>(st, ctrl); }

// ---- CNOT, target = wave bit WB, control = per-thread bool ----
// Only ctrl==1 threads exchange (partner has identical ctrl: control bit != WB bit).
template<int WB>
__device__ __forceinline__ void cnot_wave(St& st, bool ctrl, int t, float2* xbuf){
  const int partner = t ^ (64 << WB);
  __syncthreads();
  if (ctrl) stw_impl<0, 0>(st, xbuf, t);
  __syncthreads();
  if (ctrl) ldr_swap_impl<0, 0>(st, xbuf, partner);
  __syncthreads();
  if (ctrl) stw_impl<16, 0>(st, xbuf, t);
  __syncthreads();
  if (ctrl) ldr_swap_impl<16, 0>(st, xbuf, partner);
}

// ---- CNOT(14,0): control local bit0 (odd k), target wave bit3 (partner t^512) ----
template<int K>
__device__ __forceinline__ void q14_w_impl(St& st, float2* xbuf, int t){
  if constexpr (K < CHUNK){
    xbuf[K*BLOCK + t] = st.g<2*K + 1>();
    q14_w_impl<K+1>(st, xbuf, t);
  }
}
template<int K>
__device__ __forceinline__ void q14_r_impl(St& st, const float2* xbuf, int partner){
  if constexpr (K < CHUNK){
    st.g<2*K + 1>() = xbuf[K*BLOCK + partner];
    q14_r_impl<K+1>(st, xbuf, partner);
  }
}
__device__ __forceinline__ void cnot_q14(St& st, int t, float2* xbuf){
  const int partner = t ^ 512;
  __syncthreads();
  q14_w_impl<0>(st, xbuf, t);
  __syncthreads();
  q14_r_impl<0>(st, xbuf, partner);
}

// ---- initial product state ----
template<int K>
__device__ __forceinline__ void init_impl(St& st, float hp,
                                          float lc0, float lc1, float lc2, float lc3, float lc4,
                                          float ls0, float ls1, float ls2, float ls3, float ls4){
  if constexpr (K < 32){
    float v = hp;
    v *= (K & 16) ? ls0 : lc0;
    v *= (K & 8)  ? ls1 : lc1;
    v *= (K & 4)  ? ls2 : lc2;
    v *= (K & 2)  ? ls3 : lc3;
    v *= (K & 1)  ? ls4 : lc4;
    st.g<K>() = make_float2(v, 0.f);
    init_impl<K+1>(st, hp, lc0,lc1,lc2,lc3,lc4, ls0,ls1,ls2,ls3,ls4);
  }
}

// ---- final |amp|^2 sum ----
template<int K>
__device__ __forceinline__ float sumsq_impl(St& st, float acc){
  if constexpr (K < 32){
    float2 A = st.g<K>();
    return sumsq_impl<K+1>(st, acc + A.x*A.x + A.y*A.y);
  } else return acc;
}

__global__ __launch_bounds__(BLOCK, 4)
void qdarts_kernel(const float* __restrict__ x,     // [64,15]
                   const float* __restrict__ P,     // [4,15,1,4]
                   const float* __restrict__ Q,     // [4,15,4,3]
                   const float* __restrict__ rot,   // [60]
                   const float* __restrict__ gn,    // [4,15,3]
                   float* __restrict__ out)         // [64,4]
{
  __shared__ float2 xbuf[CHUNK * BLOCK];   // 128 KB exchange buffer
  __shared__ float  umat[60 * 8];          // 60 gate matrices
  __shared__ float  part[16];

  const int t    = threadIdx.x;
  const int b    = blockIdx.x;
  const int lane = t & 63;
  const int wave = t >> 6;

  // ---- 1. gate selection + matrices (one thread per (layer,qubit)) ----
  if (t < 60){
    const int idx = t;                         // idx = l*15 + q
    const float* Pv = P  + idx*4;
    const float* Qv = Q  + idx*12;
    const float* gv = gn + idx*3;
    int g = 0; float best = -1e30f;
    #pragma unroll
    for (int j = 0; j < 3; j++){
      float lg = Pv[0]*Qv[0*3+j] + Pv[1]*Qv[1*3+j] + Pv[2]*Qv[2*3+j] + Pv[3]*Qv[3*3+j] + gv[j];
      if (lg > best){ best = lg; g = j; }      // first-max, same as jnp.argmax
    }
    const float half = rot[idx] * 0.5f;
    const float c = cosf(half), s = sinf(half);
    float m0,m1,m2,m3,m4,m5,m6,m7;
    if (g == 0){        // RX: [[c, -is],[-is, c]]
      m0=c; m1=0.f; m2=0.f; m3=-s; m4=0.f; m5=-s; m6=c; m7=0.f;
    } else if (g == 1){ // RY: [[c, -s],[s, c]]
      m0=c; m1=0.f; m2=-s; m3=0.f; m4=s; m5=0.f; m6=c; m7=0.f;
    } else {            // RZ: [[e^-iθ/2, 0],[0, e^iθ/2]]
      m0=c; m1=-s; m2=0.f; m3=0.f; m4=0.f; m5=0.f; m6=c; m7=s;
    }
    umat[idx*8+0]=m0; umat[idx*8+1]=m1; umat[idx*8+2]=m2; umat[idx*8+3]=m3;
    umat[idx*8+4]=m4; umat[idx*8+5]=m5; umat[idx*8+6]=m6; umat[idx*8+7]=m7;
  }
  __syncthreads();

  // ---- 2. initial state = RY-encoded product state (real) ----
  // m = (t<<5)|k ; qubit q <-> m-bit (14-q). q in [0,9] <-> t-bit (9-q); q in [10,14] <-> k-bit (14-q).
  const float* xb = x + b*15;
  float hp = 1.f;
  #pragma unroll
  for (int q = 0; q < 10; q++){
    const float h = xb[q]*0.5f;
    hp *= ((t >> (9-q)) & 1) ? sinf(h) : cosf(h);
  }
  float lc0,lc1,lc2,lc3,lc4, ls0,ls1,ls2,ls3,ls4;
  { float h;
    h = xb[10]*0.5f; lc0 = cosf(h); ls0 = sinf(h);
    h = xb[11]*0.5f; lc1 = cosf(h); ls1 = sinf(h);
    h = xb[12]*0.5f; lc2 = cosf(h); ls2 = sinf(h);
    h = xb[13]*0.5f; lc3 = cosf(h); ls3 = sinf(h);
    h = xb[14]*0.5f; lc4 = cosf(h); ls4 = sinf(h);
  }
  St st;
  init_impl<0>(st, hp, lc0,lc1,lc2,lc3,lc4, ls0,ls1,ls2,ls3,ls4);

  // ---- 3. layers ----
  for (int l = 0; l < 4; l++){
    const float* U = umat + l*15*8;
    // rotations (commuting, reordered by locality). qubit q -> m-bit 14-q.
    rot_local<4>(st, U + 10*8);
    rot_local<3>(st, U + 11*8);
    rot_local<2>(st, U + 12*8);
    rot_local<1>(st, U + 13*8);
    rot_local<0>(st, U + 14*8);
    rot_lane<5>(st, U + 4*8, lane);
    rot_lane<4>(st, U + 5*8, lane);
    rot_lane<3>(st, U + 6*8, lane);
    rot_lane<2>(st, U + 7*8, lane);
    rot_lane<1>(st, U + 8*8, lane);
    rot_lane<0>(st, U + 9*8, lane);
    rot_wave<3>(st, U + 0*8, t, xbuf);
    rot_wave<2>(st, U + 1*8, t, xbuf);
    rot_wave<1>(st, U + 2*8, t, xbuf);
    rot_wave<0>(st, U + 3*8, t, xbuf);
    // CNOT ring, reference order q = 0..14 (adjacent CNOTs do not commute)
    cnot_wave<2>(st, (t >> 9) & 1, t, xbuf);   // q=0 : c=m14(w3), t=m13(w2)
    cnot_wave<1>(st, (t >> 8) & 1, t, xbuf);   // q=1 : c=m13(w2), t=m12(w1)
    cnot_wave<0>(st, (t >> 7) & 1, t, xbuf);   // q=2 : c=m12(w1), t=m11(w0)
    cnot_shfl<32>(st, (t >> 6) & 1);           // q=3 : c=m11(w0), t=m10(l5)
    cnot_shfl<16>(st, (lane >> 5) & 1);        // q=4 : c=m10(l5), t=m9(l4)
    cnot_shfl<8> (st, (lane >> 4) & 1);        // q=5
    cnot_shfl<4> (st, (lane >> 3) & 1);        // q=6
    cnot_shfl<2> (st, (lane >> 2) & 1);        // q=7
    cnot_shfl<1> (st, (lane >> 1) & 1);        // q=8 : c=m6(l1), t=m5(l0)
    cnot_cl<4>(st, (bool)(lane & 1));          // q=9 : c=m5(l0), t=m4(k4)
    cnot_local<4,3>(st);                       // q=10
    cnot_local<3,2>(st);                       // q=11
    cnot_local<2,1>(st);                       // q=12
    cnot_local<1,0>(st);                       // q=13
    cnot_q14(st, t, xbuf);                     // q=14: c=m0(k0), t=m14(w3)
  }

  // ---- 4. class probabilities: class = m>>13 = wave>>2 ----
  float s = sumsq_impl<0>(st, 0.f);
  #pragma unroll
  for (int off = 32; off > 0; off >>= 1) s += __shfl_down(s, off, 64);
  if (lane == 0) part[wave] = s;
  __syncthreads();
  if (t < 4){
    out[b*4 + t] = part[4*t] + part[4*t+1] + part[4*t+2] + part[4*t+3];
  }
}

extern "C" void kernel_launch(void* const* d_in, const int* in_sizes, int n_in,
                              void* d_out, int out_size, void* d_ws, size_t ws_size,
                              hipStream_t stream) {
  const float* x   = (const float*)d_in[0];
  const float* P   = (const float*)d_in[1];
  const float* Q   = (const float*)d_in[2];
  const float* rot = (const float*)d_in[3];
  const float* gn  = (const float*)d_in[4];
  float* out = (float*)d_out;
  hipLaunchKernelGGL(qdarts_kernel, dim3(64), dim3(BLOCK), 0, stream,
                     x, P, Q, rot, gn, out);
}

// Round 6
// 225.755 us; speedup vs baseline: 8.2785x; 8.2785x over previous
//
#include <hip/hip_runtime.h>

#define BLOCK 512    // 8 waves of 64 -> hard VGPR ceiling 256/wave
#define NAMPS 64     // amps per thread (128 VGPRs of state)
#define CHUNK 32     // amps per LDS exchange phase (128 KB buffer)

// ---------- state: 64 named float2 members, compile-time indexed ----------
struct St {
  float2 a0,a1,a2,a3,a4,a5,a6,a7,a8,a9,a10,a11,a12,a13,a14,a15,
         a16,a17,a18,a19,a20,a21,a22,a23,a24,a25,a26,a27,a28,a29,a30,a31,
         a32,a33,a34,a35,a36,a37,a38,a39,a40,a41,a42,a43,a44,a45,a46,a47,
         a48,a49,a50,a51,a52,a53,a54,a55,a56,a57,a58,a59,a60,a61,a62,a63;
  template<int I> __device__ __forceinline__ float2& g(){
    if constexpr (I==0) return a0;   else if constexpr (I==1) return a1;
    else if constexpr (I==2) return a2;   else if constexpr (I==3) return a3;
    else if constexpr (I==4) return a4;   else if constexpr (I==5) return a5;
    else if constexpr (I==6) return a6;   else if constexpr (I==7) return a7;
    else if constexpr (I==8) return a8;   else if constexpr (I==9) return a9;
    else if constexpr (I==10) return a10; else if constexpr (I==11) return a11;
    else if constexpr (I==12) return a12; else if constexpr (I==13) return a13;
    else if constexpr (I==14) return a14; else if constexpr (I==15) return a15;
    else if constexpr (I==16) return a16; else if constexpr (I==17) return a17;
    else if constexpr (I==18) return a18; else if constexpr (I==19) return a19;
    else if constexpr (I==20) return a20; else if constexpr (I==21) return a21;
    else if constexpr (I==22) return a22; else if constexpr (I==23) return a23;
    else if constexpr (I==24) return a24; else if constexpr (I==25) return a25;
    else if constexpr (I==26) return a26; else if constexpr (I==27) return a27;
    else if constexpr (I==28) return a28; else if constexpr (I==29) return a29;
    else if constexpr (I==30) return a30; else if constexpr (I==31) return a31;
    else if constexpr (I==32) return a32; else if constexpr (I==33) return a33;
    else if constexpr (I==34) return a34; else if constexpr (I==35) return a35;
    else if constexpr (I==36) return a36; else if constexpr (I==37) return a37;
    else if constexpr (I==38) return a38; else if constexpr (I==39) return a39;
    else if constexpr (I==40) return a40; else if constexpr (I==41) return a41;
    else if constexpr (I==42) return a42; else if constexpr (I==43) return a43;
    else if constexpr (I==44) return a44; else if constexpr (I==45) return a45;
    else if constexpr (I==46) return a46; else if constexpr (I==47) return a47;
    else if constexpr (I==48) return a48; else if constexpr (I==49) return a49;
    else if constexpr (I==50) return a50; else if constexpr (I==51) return a51;
    else if constexpr (I==52) return a52; else if constexpr (I==53) return a53;
    else if constexpr (I==54) return a54; else if constexpr (I==55) return a55;
    else if constexpr (I==56) return a56; else if constexpr (I==57) return a57;
    else if constexpr (I==58) return a58; else if constexpr (I==59) return a59;
    else if constexpr (I==60) return a60; else if constexpr (I==61) return a61;
    else if constexpr (I==62) return a62; else return a63;
  }
};

__device__ __forceinline__ float2 cmadd2(float2 u, float2 a, float2 v, float2 b){
  // u*a + v*b (complex)
  return make_float2(u.x*a.x - u.y*a.y + v.x*b.x - v.y*b.y,
                     u.x*a.y + u.y*a.x + v.x*b.y + v.y*b.x);
}

// ================= template-recursive gate bodies (all indices compile-time) =================

// ---- rotation on local k-bit BL (0..5) ----
template<int BL, int K>
__device__ __forceinline__ void rot_local_impl(St& st, float2 u00, float2 u01, float2 u10, float2 u11){
  if constexpr (K < NAMPS){
    if constexpr (!(K & (1<<BL))){
      constexpr int K1 = K | (1<<BL);
      float2 x0 = st.g<K>(), x1 = st.g<K1>();
      st.g<K>()  = cmadd2(u00, x0, u01, x1);
      st.g<K1>() = cmadd2(u10, x0, u11, x1);
    }
    rot_local_impl<BL, K+1>(st, u00, u01, u10, u11);
  }
}
template<int BL>
__device__ __forceinline__ void rot_local(St& st, const float* u){
  float2 u00 = make_float2(u[0],u[1]), u01 = make_float2(u[2],u[3]);
  float2 u10 = make_float2(u[4],u[5]), u11 = make_float2(u[6],u[7]);
  rot_local_impl<BL, 0>(st, u00, u01, u10, u11);
}

// ---- rotation on lane bit LB (0..5): wave shuffle ----
template<int LB, int K>
__device__ __forceinline__ void rot_lane_impl(St& st, float2 ua, float2 ub){
  if constexpr (K < NAMPS){
    float2 A = st.g<K>();
    float2 p;
    p.x = __shfl_xor(A.x, 1<<LB, 64);
    p.y = __shfl_xor(A.y, 1<<LB, 64);
    st.g<K>() = cmadd2(ua, A, ub, p);
    rot_lane_impl<LB, K+1>(st, ua, ub);
  }
}
template<int LB>
__device__ __forceinline__ void rot_lane(St& st, const float* u, int lane){
  const int bit = (lane >> LB) & 1;
  float2 u00 = make_float2(u[0],u[1]), u01 = make_float2(u[2],u[3]);
  float2 u10 = make_float2(u[4],u[5]), u11 = make_float2(u[6],u[7]);
  float2 ua = bit ? u11 : u00;
  float2 ub = bit ? u10 : u01;
  rot_lane_impl<LB, 0>(st, ua, ub);
}

// ---- LDS staging helpers (compile-time chunk index) ----
template<int Base, int K>
__device__ __forceinline__ void stw_impl(St& st, float2* xbuf, int t){
  if constexpr (K < CHUNK){
    xbuf[K*BLOCK + t] = st.g<Base + K>();
    stw_impl<Base, K+1>(st, xbuf, t);
  }
}
template<int Base, int K>
__device__ __forceinline__ void ldr_rot_impl(St& st, const float2* xbuf, int partner, float2 ua, float2 ub){
  if constexpr (K < CHUNK){
    float2 p = xbuf[K*BLOCK + partner];
    float2 A = st.g<Base + K>();
    st.g<Base + K>() = cmadd2(ua, A, ub, p);
    ldr_rot_impl<Base, K+1>(st, xbuf, partner, ua, ub);
  }
}
template<int Base, int K>
__device__ __forceinline__ void ldr_mov_impl(St& st, const float2* xbuf, int src){
  if constexpr (K < CHUNK){
    st.g<Base + K>() = xbuf[K*BLOCK + src];
    ldr_mov_impl<Base, K+1>(st, xbuf, src);
  }
}

// ---- rotation on wave bit WB (0..2): LDS exchange, 2 phases of 32 ----
template<int WB>
__device__ __forceinline__ void rot_wave(St& st, const float* u, int t, float2* xbuf){
  const int partner = t ^ (64 << WB);
  const int bit = (t >> (6 + WB)) & 1;
  float2 u00 = make_float2(u[0],u[1]), u01 = make_float2(u[2],u[3]);
  float2 u10 = make_float2(u[4],u[5]), u11 = make_float2(u[6],u[7]);
  float2 ua = bit ? u11 : u00;
  float2 ub = bit ? u10 : u01;
  __syncthreads();                       // prior xbuf readers done
  stw_impl<0, 0>(st, xbuf, t);
  __syncthreads();
  ldr_rot_impl<0, 0>(st, xbuf, partner, ua, ub);
  __syncthreads();
  stw_impl<32, 0>(st, xbuf, t);
  __syncthreads();
  ldr_rot_impl<32, 0>(st, xbuf, partner, ua, ub);
}

// ---- fused CNOT wave chain (ring q0,q1): one permutation exchange ----
// forward: w1^=w2; then w0^=w1(new).  inverse src_wave = w ^ ((w>>1)&3)
__device__ __forceinline__ void cnot_wavechain(St& st, int t, float2* xbuf){
  const int wave = t >> 6, lane = t & 63;
  const int src = ((wave ^ ((wave >> 1) & 3)) << 6) | lane;
  __syncthreads();
  stw_impl<0, 0>(st, xbuf, t);
  __syncthreads();
  ldr_mov_impl<0, 0>(st, xbuf, src);
  __syncthreads();
  stw_impl<32, 0>(st, xbuf, t);
  __syncthreads();
  ldr_mov_impl<32, 0>(st, xbuf, src);
}

// ---- fused CNOT lane chain (ring q2..q7): one shuffle sweep ----
// forward: l5^=w0; l4^=l5'; ... l0^=l1'.  inverse src = lane ^ ((lane>>1)&31) ^ (w0<<5)
template<int K>
__device__ __forceinline__ void lanechain_impl(St& st, int src){
  if constexpr (K < NAMPS){
    float2 A = st.g<K>();
    float2 p;
    p.x = __shfl(A.x, src, 64);
    p.y = __shfl(A.y, src, 64);
    st.g<K>() = p;
    lanechain_impl<K+1>(st, src);
  }
}
__device__ __forceinline__ void cnot_lanechain(St& st, int t){
  const int lane = t & 63;
  const int w0 = (t >> 6) & 1;
  const int src = lane ^ ((lane >> 1) & 31) ^ (w0 << 5);
  lanechain_impl<0>(st, src);
}

// ---- ring q8: CNOT(c=l0, t=k5): conditional pairwise swap ----
template<int K>
__device__ __forceinline__ void q8_impl(St& st, bool ctrl){
  if constexpr (K < 32){
    constexpr int K1 = K | 32;
    float2 x0 = st.g<K>(), x1 = st.g<K1>();
    st.g<K>()  = ctrl ? x1 : x0;
    st.g<K1>() = ctrl ? x0 : x1;
    q8_impl<K+1>(st, ctrl);
  }
}

// ---- ring q9..q13: local ripple, pure compile-time register rename ----
// inverse src = k ^ ((k>>1)&31)
template<int K>
__device__ __forceinline__ void ripple_impl(St& dst, St& src){
  if constexpr (K < NAMPS){
    dst.g<K>() = src.g<K ^ ((K>>1) & 31)>();
    ripple_impl<K+1>(dst, src);
  }
}

// ---- ring q14: CNOT(c=k0, t=w2): half-exchange of odd-k amps, partner t^256 ----
template<int K>
__device__ __forceinline__ void q14_w_impl(St& st, float2* xbuf, int t){
  if constexpr (K < 32){
    xbuf[K*BLOCK + t] = st.g<2*K + 1>();
    q14_w_impl<K+1>(st, xbuf, t);
  }
}
template<int K>
__device__ __forceinline__ void q14_r_impl(St& st, const float2* xbuf, int partner){
  if constexpr (K < 32){
    st.g<2*K + 1>() = xbuf[K*BLOCK + partner];
    q14_r_impl<K+1>(st, xbuf, partner);
  }
}
__device__ __forceinline__ void cnot_q14(St& st, int t, float2* xbuf){
  const int partner = t ^ 256;
  __syncthreads();
  q14_w_impl<0>(st, xbuf, t);
  __syncthreads();
  q14_r_impl<0>(st, xbuf, partner);
}

// ---- initial product state (named scalars, no address-taken locals) ----
template<int K>
__device__ __forceinline__ void init_impl(St& st, float hp,
                                          float lc0, float lc1, float lc2, float lc3, float lc4, float lc5,
                                          float ls0, float ls1, float ls2, float ls3, float ls4, float ls5){
  if constexpr (K < NAMPS){
    float v = hp;
    v *= (K & 32) ? ls5 : lc5;
    v *= (K & 16) ? ls4 : lc4;
    v *= (K & 8)  ? ls3 : lc3;
    v *= (K & 4)  ? ls2 : lc2;
    v *= (K & 2)  ? ls1 : lc1;
    v *= (K & 1)  ? ls0 : lc0;
    st.g<K>() = make_float2(v, 0.f);
    init_impl<K+1>(st, hp, lc0,lc1,lc2,lc3,lc4,lc5, ls0,ls1,ls2,ls3,ls4,ls5);
  }
}

// ---- final |amp|^2 sum ----
template<int K>
__device__ __forceinline__ float sumsq_impl(St& st, float acc){
  if constexpr (K < NAMPS){
    float2 A = st.g<K>();
    return sumsq_impl<K+1>(st, acc + A.x*A.x + A.y*A.y);
  } else return acc;
}

__global__ __attribute__((amdgpu_flat_work_group_size(BLOCK,BLOCK), amdgpu_waves_per_eu(2,2)))
void qdarts_kernel(const float* __restrict__ x,     // [64,15]
                   const float* __restrict__ P,     // [4,15,1,4]
                   const float* __restrict__ Q,     // [4,15,4,3]
                   const float* __restrict__ rot,   // [60]
                   const float* __restrict__ gn,    // [4,15,3]
                   float* __restrict__ out)         // [64,4]
{
  __shared__ float2 xbuf[CHUNK * BLOCK];   // 128 KB exchange buffer (1 block/CU)
  __shared__ float  umat[60 * 8];          // 60 gate matrices
  __shared__ float  part[8];

  const int t    = threadIdx.x;
  const int b    = blockIdx.x;
  const int lane = t & 63;
  const int wave = t >> 6;

  // ---- 1. gate selection + matrices (one thread per (layer,qubit)) ----
  if (t < 60){
    const int idx = t;                         // idx = l*15 + q
    const float* Pv = P  + idx*4;
    const float* Qv = Q  + idx*12;
    const float* gv = gn + idx*3;
    int g = 0; float best = -1e30f;
    #pragma unroll
    for (int j = 0; j < 3; j++){
      float lg = Pv[0]*Qv[0*3+j] + Pv[1]*Qv[1*3+j] + Pv[2]*Qv[2*3+j] + Pv[3]*Qv[3*3+j] + gv[j];
      if (lg > best){ best = lg; g = j; }      // first-max, same as jnp.argmax
    }
    const float half = rot[idx] * 0.5f;
    const float c = cosf(half), s = sinf(half);
    float m0,m1,m2,m3,m4,m5,m6,m7;
    if (g == 0){        // RX
      m0=c; m1=0.f; m2=0.f; m3=-s; m4=0.f; m5=-s; m6=c; m7=0.f;
    } else if (g == 1){ // RY
      m0=c; m1=0.f; m2=-s; m3=0.f; m4=s; m5=0.f; m6=c; m7=0.f;
    } else {            // RZ
      m0=c; m1=-s; m2=0.f; m3=0.f; m4=0.f; m5=0.f; m6=c; m7=s;
    }
    umat[idx*8+0]=m0; umat[idx*8+1]=m1; umat[idx*8+2]=m2; umat[idx*8+3]=m3;
    umat[idx*8+4]=m4; umat[idx*8+5]=m5; umat[idx*8+6]=m6; umat[idx*8+7]=m7;
  }
  __syncthreads();

  // ---- 2. initial state = RY-encoded product state (real) ----
  // m = (t<<6)|k ; qubit q <-> m-bit (14-q). q in [0,8] <-> t-bit (8-q); q in [9,14] <-> k-bit (14-q).
  const float* xb = x + b*15;
  float hp = 1.f;
  #pragma unroll
  for (int q = 0; q < 9; q++){
    const float h = xb[q]*0.5f;
    hp *= ((t >> (8-q)) & 1) ? sinf(h) : cosf(h);
  }
  // k-bit j <-> qubit 14-j
  float lc0,lc1,lc2,lc3,lc4,lc5, ls0,ls1,ls2,ls3,ls4,ls5;
  { float h;
    h = xb[14]*0.5f; lc0 = cosf(h); ls0 = sinf(h);
    h = xb[13]*0.5f; lc1 = cosf(h); ls1 = sinf(h);
    h = xb[12]*0.5f; lc2 = cosf(h); ls2 = sinf(h);
    h = xb[11]*0.5f; lc3 = cosf(h); ls3 = sinf(h);
    h = xb[10]*0.5f; lc4 = cosf(h); ls4 = sinf(h);
    h = xb[9] *0.5f; lc5 = cosf(h); ls5 = sinf(h);
  }
  St st;
  init_impl<0>(st, hp, lc0,lc1,lc2,lc3,lc4,lc5, ls0,ls1,ls2,ls3,ls4,ls5);

  // ---- 3. layers ----
  for (int l = 0; l < 4; l++){
    const float* U = umat + l*15*8;
    // rotations (commuting). qubit q -> m-bit 14-q.
    rot_local<5>(st, U + 9*8);     // q9  <-> k5
    rot_local<4>(st, U + 10*8);
    rot_local<3>(st, U + 11*8);
    rot_local<2>(st, U + 12*8);
    rot_local<1>(st, U + 13*8);
    rot_local<0>(st, U + 14*8);    // q14 <-> k0
    rot_lane<5>(st, U + 3*8, lane);   // q3 <-> l5
    rot_lane<4>(st, U + 4*8, lane);
    rot_lane<3>(st, U + 5*8, lane);
    rot_lane<2>(st, U + 6*8, lane);
    rot_lane<1>(st, U + 7*8, lane);
    rot_lane<0>(st, U + 8*8, lane);   // q8 <-> l0
    rot_wave<2>(st, U + 0*8, t, xbuf);  // q0 <-> w2
    rot_wave<1>(st, U + 1*8, t, xbuf);  // q1 <-> w1
    rot_wave<0>(st, U + 2*8, t, xbuf);  // q2 <-> w0
    // CNOT ring in reference order, fused by tier:
    cnot_wavechain(st, t, xbuf);        // q0,q1
    cnot_lanechain(st, t);              // q2..q7
    q8_impl<0>(st, (bool)(lane & 1));   // q8
    { St tmp; ripple_impl<0>(tmp, st); st = tmp; }  // q9..q13 (register rename)
    cnot_q14(st, t, xbuf);              // q14
  }

  // ---- 4. class probabilities: class = m14,m13 = wave>>1 ----
  float s = sumsq_impl<0>(st, 0.f);
  #pragma unroll
  for (int off = 32; off > 0; off >>= 1) s += __shfl_down(s, off, 64);
  if (lane == 0) part[wave] = s;
  __syncthreads();
  if (t < 4){
    out[b*4 + t] = part[2*t] + part[2*t+1];
  }
}

extern "C" void kernel_launch(void* const* d_in, const int* in_sizes, int n_in,
                              void* d_out, int out_size, void* d_ws, size_t ws_size,
                              hipStream_t stream) {
  const float* x   = (const float*)d_in[0];
  const float* P   = (const float*)d_in[1];
  const float* Q   = (const float*)d_in[2];
  const float* rot = (const float*)d_in[3];
  const float* gn  = (const float*)d_in[4];
  float* out = (float*)d_out;
  hipLaunchKernelGGL(qdarts_kernel, dim3(64), dim3(BLOCK), 0, stream,
                     x, P, Q, rot, gn, out);
}